// Round 1
// baseline (267.802 us; speedup 1.0000x reference)
//
#include <hip/hip_runtime.h>

namespace {
constexpr int B   = 2;
constexpr int CIN = 64;
constexpr int H   = 32;
constexpr int W   = 192;
constexpr int DM  = 32;   // d_model
constexpr int NH  = 8;    // heads
constexpr int C   = 4;    // depth per head
constexpr int QS  = 24;
constexpr int FL  = 8;
constexpr int T   = 192;          // width (no pad needed: 192 % 24 == 0)
constexpr int TP  = T + 2 * FL;   // 208 padded time
constexpr int M   = T / QS;       // 8 windows
constexpr int F   = 2 * FL + QS;  // 40 window length
constexpr int HF  = H * F;        // 1280 keys per group

// workspace layout (floats)
constexpr size_t Q_SZ  = (size_t)B * DM * H * T;      // 393216
constexpr size_t KP_SZ = (size_t)B * NH * C * H * TP; // 425984
constexpr size_t Q_OFF = 0;
constexpr size_t K_OFF = Q_OFF + Q_SZ;
constexpr size_t V_OFF = K_OFF + KP_SZ;
constexpr size_t O_OFF = V_OFF + KP_SZ;
// total floats = 1,638,400 (~6.55 MB)

// strides of the faithful as_strided-bug gather (uses T=192, not TP=208!)
constexpr int S0 = NH * C * H * T; // 196608
constexpr int S1 = C * H * T;      // 24576
constexpr int S2 = H * T;          // 6144
constexpr int S3 = T;              // 192
}

// ---- zero the 8-left/8-right pad columns of k_pad / v_pad ----------------
__global__ __launch_bounds__(256) void zero_pads_k(float* __restrict__ ws) {
  int t = blockIdx.x * 256 + threadIdx.x;       // 0..32767
  int row = t >> 4;                             // 0..2047  (B*NH*C*H rows)
  int p = t & 15;
  int col = (p < 8) ? p : (192 + p);            // 0..7 or 200..207
  size_t addr = (size_t)row * TP + col;
  ws[K_OFF + addr] = 0.f;
  ws[V_OFF + addr] = 0.f;
}

// ---- fused q/k/v conv3x3 (SAME), writes q linear + k/v padded ------------
// grid: B*32*32 blocks (b, co, y), 192 threads = one x position each
__global__ __launch_bounds__(192) void qkv_conv_k(
    const float* __restrict__ x,
    const float* __restrict__ qw, const float* __restrict__ qb,
    const float* __restrict__ kw, const float* __restrict__ kb,
    const float* __restrict__ vw, const float* __restrict__ vb,
    float* __restrict__ ws) {
  int bid = blockIdx.x;
  int y  = bid & 31;
  int co = (bid >> 5) & 31;
  int b  = bid >> 10;
  int xp = threadIdx.x;

  float aq = qb[co], ak = kb[co], av = vb[co];
  const float* xb  = x  + (size_t)b * CIN * H * W;
  const float* qwb = qw + co * CIN * 9;
  const float* kwb = kw + co * CIN * 9;
  const float* vwb = vw + co * CIN * 9;

  for (int ci = 0; ci < CIN; ++ci) {
    const float* xc  = xb + ci * H * W;
    const float* qwc = qwb + ci * 9;
    const float* kwc = kwb + ci * 9;
    const float* vwc = vwb + ci * 9;
#pragma unroll
    for (int dy = 0; dy < 3; ++dy) {
      int yy = y + dy - 1;
      if (yy < 0 || yy >= H) continue;          // wave-uniform (y uniform per block)
      const float* xr = xc + yy * W;
#pragma unroll
      for (int dx = 0; dx < 3; ++dx) {
        int xx = xp + dx - 1;
        float xv = (xx >= 0 && xx < W) ? xr[xx] : 0.f;
        aq = fmaf(xv, qwc[dy * 3 + dx], aq);
        ak = fmaf(xv, kwc[dy * 3 + dx], ak);
        av = fmaf(xv, vwc[dy * 3 + dx], av);
      }
    }
  }
  ws[Q_OFF + (((size_t)(b * DM + co) * H + y) * T) + xp] = aq;
  int h = co >> 2, c4 = co & 3;
  size_t pa = (((size_t)((b * NH + h) * C + c4) * H + y) * TP) + FL + xp;
  ws[K_OFF + pa] = ak;
  ws[V_OFF + pa] = av;
}

// ---- attention: one block per (group, 256-row slice) ---------------------
// group g = (b*8 + h)*8 + m ; rows r = hh*24 + qi  (768 per group)
__global__ __launch_bounds__(256) void attn_k(float* __restrict__ ws) {
  const float* qbuf = ws + Q_OFF;
  const float* kp   = ws + K_OFF;
  const float* vp   = ws + V_OFF;
  float*       ob   = ws + O_OFF;

  __shared__ __align__(16) float Kt[HF * 4];
  __shared__ __align__(16) float Vt[HF * 4];

  int g = blockIdx.x;
  int b = g >> 6, h = (g >> 3) & 7, m = g & 7;
  int tid = threadIdx.x;

  // faithful drift-gather: storage-linear index into padded flat buffers
  int base = b * S0 + h * S1 + m * QS;
  for (int e = tid; e < HF * 4; e += 256) {      // 20 iters
    int j  = e >> 2, ci = e & 3;
    int hh = j / F, f = j - hh * F;
    int addr = base + ci * S2 + hh * S3 + f;
    Kt[e] = kp[addr];
    Vt[e] = vp[addr];
  }
  __syncthreads();

  int r  = blockIdx.y * 256 + tid;              // 0..767
  int hh = r / QS, qi = r - hh * QS;
  size_t qidx = (((size_t)(b * DM + h * C) * H + hh) * T) + m * QS + qi;
  float q0 = qbuf[qidx]             * 0.5f;
  float q1 = qbuf[qidx + H * T]     * 0.5f;
  float q2 = qbuf[qidx + 2 * H * T] * 0.5f;
  float q3 = qbuf[qidx + 3 * H * T] * 0.5f;

  // pass 1: row max
  float mx = -1e30f;
#pragma unroll 8
  for (int j = 0; j < HF; ++j) {
    float4 k4 = *reinterpret_cast<const float4*>(Kt + (j << 2));
    float l = fmaf(q0, k4.x, fmaf(q1, k4.y, fmaf(q2, k4.z, q3 * k4.w)));
    mx = fmaxf(mx, l);
  }

  // pass 2: exp-sum + PV accumulate
  float s = 0.f, o0 = 0.f, o1 = 0.f, o2 = 0.f, o3 = 0.f;
#pragma unroll 4
  for (int j = 0; j < HF; ++j) {
    float4 k4 = *reinterpret_cast<const float4*>(Kt + (j << 2));
    float4 v4 = *reinterpret_cast<const float4*>(Vt + (j << 2));
    float l = fmaf(q0, k4.x, fmaf(q1, k4.y, fmaf(q2, k4.z, q3 * k4.w)));
    float e = __expf(l - mx);
    s += e;
    o0 = fmaf(e, v4.x, o0);
    o1 = fmaf(e, v4.y, o1);
    o2 = fmaf(e, v4.z, o2);
    o3 = fmaf(e, v4.w, o3);
  }
  float inv = 1.0f / s;
  size_t oidx = (((size_t)(b * DM + h * C) * H + hh) * T) + m * QS + qi;
  ob[oidx]             = o0 * inv;
  ob[oidx + H * T]     = o1 * inv;
  ob[oidx + 2 * H * T] = o2 * inv;
  ob[oidx + 3 * H * T] = o3 * inv;
}

// ---- output conv3x3 (32 -> 64, no bias) ----------------------------------
__global__ __launch_bounds__(192) void out_conv_k(const float* __restrict__ ws,
                                                  const float* __restrict__ ow,
                                                  float* __restrict__ out) {
  const float* ob = ws + O_OFF;
  int bid = blockIdx.x;
  int y  = bid & 31;
  int co = (bid >> 5) & 63;
  int b  = bid >> 11;
  int xp = threadIdx.x;

  float acc = 0.f;
  const float* obb = ob + (size_t)b * DM * H * W;
  const float* owb = ow + co * DM * 9;
  for (int ci = 0; ci < DM; ++ci) {
    const float* oc = obb + ci * H * W;
    const float* wc = owb + ci * 9;
#pragma unroll
    for (int dy = 0; dy < 3; ++dy) {
      int yy = y + dy - 1;
      if (yy < 0 || yy >= H) continue;
      const float* orow = oc + yy * W;
#pragma unroll
      for (int dx = 0; dx < 3; ++dx) {
        int xx = xp + dx - 1;
        float xv = (xx >= 0 && xx < W) ? orow[xx] : 0.f;
        acc = fmaf(xv, wc[dy * 3 + dx], acc);
      }
    }
  }
  out[(((size_t)(b * 64 + co) * H + y) * W) + xp] = acc;
}

extern "C" void kernel_launch(void* const* d_in, const int* in_sizes, int n_in,
                              void* d_out, int out_size, void* d_ws, size_t ws_size,
                              hipStream_t stream) {
  const float* x  = (const float*)d_in[0];
  const float* qw = (const float*)d_in[1];
  const float* qb = (const float*)d_in[2];
  const float* kw = (const float*)d_in[3];
  const float* kb = (const float*)d_in[4];
  const float* vw = (const float*)d_in[5];
  const float* vb = (const float*)d_in[6];
  const float* ow = (const float*)d_in[7];
  float* out = (float*)d_out;
  float* ws  = (float*)d_ws;

  hipLaunchKernelGGL(zero_pads_k, dim3(128), dim3(256), 0, stream, ws);
  hipLaunchKernelGGL(qkv_conv_k, dim3(B * 32 * 32), dim3(192), 0, stream,
                     x, qw, qb, kw, kb, vw, vb, ws);
  hipLaunchKernelGGL(attn_k, dim3(128, 3), dim3(256), 0, stream, ws);
  hipLaunchKernelGGL(out_conv_k, dim3(B * 64 * 32), dim3(192), 0, stream, ws, ow, out);
}

// Round 2
// 166.048 us; speedup vs baseline: 1.6128x; 1.6128x over previous
//
#include <hip/hip_runtime.h>

namespace {
constexpr int B   = 2;
constexpr int CIN = 64;
constexpr int H   = 32;
constexpr int W   = 192;
constexpr int DM  = 32;   // d_model
constexpr int NH  = 8;    // heads
constexpr int C   = 4;    // depth per head
constexpr int QS  = 24;
constexpr int FL  = 8;
constexpr int T   = 192;          // width (192 % 24 == 0 -> no col pad)
constexpr int TP  = T + 2 * FL;   // 208
constexpr int M   = T / QS;       // 8 windows
constexpr int F   = 2 * FL + QS;  // 40 window length
constexpr int HF  = H * F;        // 1280 keys per group
constexpr int JC  = HF / 4;       // 320 keys per j-chunk

// workspace layout (floats)
constexpr size_t Q_SZ   = (size_t)B * DM * H * T;      // 393216
constexpr size_t KP_SZ  = (size_t)B * NH * C * H * TP; // 425984
constexpr size_t Q_OFF  = 0;
constexpr size_t K_OFF  = Q_OFF + Q_SZ;
constexpr size_t V_OFF  = K_OFF + KP_SZ;
constexpr size_t KV_OFF = V_OFF + KP_SZ;
constexpr size_t KV_SZ  = (size_t)B * NH * M * HF * 8; // 1310720
constexpr size_t O_OFF  = K_OFF;  // O overlaps KP (dead after build_kv)
// total ws = KV_OFF + KV_SZ = 2,555,904 floats ~ 10.2 MB

// strides of the faithful as_strided-bug gather (uses T=192, not TP=208!)
constexpr int S0 = NH * C * H * T; // 196608
constexpr int S1 = C * H * T;      // 24576
constexpr int S2 = H * T;          // 6144
constexpr int S3 = T;              // 192
}

// ---- zero the 8-left/8-right pad columns of k_pad / v_pad ----------------
__global__ __launch_bounds__(256) void zero_pads_k(float* __restrict__ ws) {
  int t = blockIdx.x * 256 + threadIdx.x;       // 0..32767
  int row = t >> 4;                             // 0..2047  (B*NH*C*H rows)
  int p = t & 15;
  int col = (p < 8) ? p : (192 + p);            // 0..7 or 200..207
  size_t addr = (size_t)row * TP + col;
  ws[K_OFF + addr] = 0.f;
  ws[V_OFF + addr] = 0.f;
}

// ---- fused q/k/v conv3x3 (SAME), writes q linear + k/v padded ------------
// grid: B*32*32 blocks (b, co, y), 192 threads = one x position each
__global__ __launch_bounds__(192) void qkv_conv_k(
    const float* __restrict__ x,
    const float* __restrict__ qw, const float* __restrict__ qb,
    const float* __restrict__ kw, const float* __restrict__ kb,
    const float* __restrict__ vw, const float* __restrict__ vb,
    float* __restrict__ ws) {
  int bid = blockIdx.x;
  int y  = bid & 31;
  int co = (bid >> 5) & 31;
  int b  = bid >> 10;
  int xp = threadIdx.x;

  float aq = qb[co], ak = kb[co], av = vb[co];
  const float* xb  = x  + (size_t)b * CIN * H * W;
  const float* qwb = qw + co * CIN * 9;
  const float* kwb = kw + co * CIN * 9;
  const float* vwb = vw + co * CIN * 9;

  for (int ci = 0; ci < CIN; ++ci) {
    const float* xc  = xb + ci * H * W;
    const float* qwc = qwb + ci * 9;
    const float* kwc = kwb + ci * 9;
    const float* vwc = vwb + ci * 9;
#pragma unroll
    for (int dy = 0; dy < 3; ++dy) {
      int yy = y + dy - 1;
      if (yy < 0 || yy >= H) continue;          // wave-uniform (y uniform per block)
      const float* xr = xc + yy * W;
#pragma unroll
      for (int dx = 0; dx < 3; ++dx) {
        int xx = xp + dx - 1;
        float xv = (xx >= 0 && xx < W) ? xr[xx] : 0.f;
        aq = fmaf(xv, qwc[dy * 3 + dx], aq);
        ak = fmaf(xv, kwc[dy * 3 + dx], ak);
        av = fmaf(xv, vwc[dy * 3 + dx], av);
      }
    }
  }
  ws[Q_OFF + (((size_t)(b * DM + co) * H + y) * T) + xp] = aq;
  int h = co >> 2, c4 = co & 3;
  size_t pa = (((size_t)((b * NH + h) * C + c4) * H + y) * TP) + FL + xp;
  ws[K_OFF + pa] = ak;
  ws[V_OFF + pa] = av;
}

// ---- build interleaved KV windows: kv[g][j][k0..k3,v0..v3] ---------------
// faithful drift-gather by storage-linear index into the padded flat buffers
__global__ __launch_bounds__(256) void build_kv_k(float* __restrict__ ws) {
  const float* kp = ws + K_OFF;
  const float* vp = ws + V_OFF;
  float* kv = ws + KV_OFF;
  int t = blockIdx.x * 256 + threadIdx.x;       // < 1,310,720
  int c  = t & 7;
  int gj = t >> 3;
  int g  = gj / HF;
  int j  = gj - g * HF;
  int b = g >> 6, h = (g >> 3) & 7, m = g & 7;
  int hh = j / F, f = j - hh * F;
  int ci = c & 3;
  const float* src = (c < 4) ? kp : vp;
  int addr = b * S0 + h * S1 + ci * S2 + hh * S3 + m * QS + f;
  kv[t] = src[addr];
}

// ---- attention: block = 4 j-chunk waves x 64 rows ------------------------
// grid (128 groups, 12 row-blocks); single-pass exp (no max: |logit| << 88)
__global__ __launch_bounds__(256) void attn_k(float* __restrict__ ws) {
  const float* qbuf = ws + Q_OFF;
  const float* kv   = ws + KV_OFF;
  float*       ob   = ws + O_OFF;

  int g  = blockIdx.x;                          // 0..127
  int rb = blockIdx.y;                          // 0..11
  int b = g >> 6, h = (g >> 3) & 7, m = g & 7;
  int tid = threadIdx.x;
  int row = tid & 63;
  int jc  = __builtin_amdgcn_readfirstlane(tid >> 6);  // wave id, SGPR

  int r  = rb * 64 + row;                       // 0..767
  int hh = r / QS, qi = r - hh * QS;
  size_t qidx = (((size_t)(b * DM + h * C) * H + hh) * T) + m * QS + qi;
  float q0 = qbuf[qidx]             * 0.5f;
  float q1 = qbuf[qidx + H * T]     * 0.5f;
  float q2 = qbuf[qidx + 2 * H * T] * 0.5f;
  float q3 = qbuf[qidx + 3 * H * T] * 0.5f;

  const float* kvp = kv + ((size_t)g * HF + (size_t)jc * JC) * 8;

  float s = 0.f, o0 = 0.f, o1 = 0.f, o2 = 0.f, o3 = 0.f;
#pragma unroll 4
  for (int j = 0; j < JC; ++j) {
    float4 k4 = *reinterpret_cast<const float4*>(kvp + j * 8);
    float4 v4 = *reinterpret_cast<const float4*>(kvp + j * 8 + 4);
    float l = fmaf(q0, k4.x, fmaf(q1, k4.y, fmaf(q2, k4.z, q3 * k4.w)));
    float e = __expf(l);
    s += e;
    o0 = fmaf(e, v4.x, o0);
    o1 = fmaf(e, v4.y, o1);
    o2 = fmaf(e, v4.z, o2);
    o3 = fmaf(e, v4.w, o3);
  }

  __shared__ float red[4][64][5];
  red[jc][row][0] = s;
  red[jc][row][1] = o0;
  red[jc][row][2] = o1;
  red[jc][row][3] = o2;
  red[jc][row][4] = o3;
  __syncthreads();

  if (tid < 64) {                               // row == tid here
    float S = 0.f, O0 = 0.f, O1 = 0.f, O2 = 0.f, O3 = 0.f;
#pragma unroll
    for (int cx = 0; cx < 4; ++cx) {
      S  += red[cx][tid][0];
      O0 += red[cx][tid][1];
      O1 += red[cx][tid][2];
      O2 += red[cx][tid][3];
      O3 += red[cx][tid][4];
    }
    float inv = 1.0f / S;
    ob[qidx]             = O0 * inv;
    ob[qidx + H * T]     = O1 * inv;
    ob[qidx + 2 * H * T] = O2 * inv;
    ob[qidx + 3 * H * T] = O3 * inv;
  }
}

// ---- output conv3x3 (32 -> 64, no bias) ----------------------------------
__global__ __launch_bounds__(192) void out_conv_k(const float* __restrict__ ws,
                                                  const float* __restrict__ ow,
                                                  float* __restrict__ out) {
  const float* ob = ws + O_OFF;
  int bid = blockIdx.x;
  int y  = bid & 31;
  int co = (bid >> 5) & 63;
  int b  = bid >> 11;
  int xp = threadIdx.x;

  float acc = 0.f;
  const float* obb = ob + (size_t)b * DM * H * W;
  const float* owb = ow + co * DM * 9;
  for (int ci = 0; ci < DM; ++ci) {
    const float* oc = obb + ci * H * W;
    const float* wc = owb + ci * 9;
#pragma unroll
    for (int dy = 0; dy < 3; ++dy) {
      int yy = y + dy - 1;
      if (yy < 0 || yy >= H) continue;
      const float* orow = oc + yy * W;
#pragma unroll
      for (int dx = 0; dx < 3; ++dx) {
        int xx = xp + dx - 1;
        float xv = (xx >= 0 && xx < W) ? orow[xx] : 0.f;
        acc = fmaf(xv, wc[dy * 3 + dx], acc);
      }
    }
  }
  out[(((size_t)(b * 64 + co) * H + y) * W) + xp] = acc;
}

extern "C" void kernel_launch(void* const* d_in, const int* in_sizes, int n_in,
                              void* d_out, int out_size, void* d_ws, size_t ws_size,
                              hipStream_t stream) {
  const float* x  = (const float*)d_in[0];
  const float* qw = (const float*)d_in[1];
  const float* qb = (const float*)d_in[2];
  const float* kw = (const float*)d_in[3];
  const float* kb = (const float*)d_in[4];
  const float* vw = (const float*)d_in[5];
  const float* vb = (const float*)d_in[6];
  const float* ow = (const float*)d_in[7];
  float* out = (float*)d_out;
  float* ws  = (float*)d_ws;

  hipLaunchKernelGGL(zero_pads_k, dim3(128), dim3(256), 0, stream, ws);
  hipLaunchKernelGGL(qkv_conv_k, dim3(B * 32 * 32), dim3(192), 0, stream,
                     x, qw, qb, kw, kb, vw, vb, ws);
  hipLaunchKernelGGL(build_kv_k, dim3(5120), dim3(256), 0, stream, ws);
  hipLaunchKernelGGL(attn_k, dim3(128, 12), dim3(256), 0, stream, ws);
  hipLaunchKernelGGL(out_conv_k, dim3(B * 64 * 32), dim3(192), 0, stream, ws, ow, out);
}

// Round 3
// 117.591 us; speedup vs baseline: 2.2774x; 1.4121x over previous
//
#include <hip/hip_runtime.h>

namespace {
constexpr int B   = 2;
constexpr int CIN = 64;
constexpr int H   = 32;
constexpr int W   = 192;
constexpr int DM  = 32;
constexpr int NH  = 8;
constexpr int C   = 4;
constexpr int QS  = 24;
constexpr int FL  = 8;
constexpr int T   = 192;
constexpr int TP  = T + 2 * FL;   // 208
constexpr int M   = T / QS;       // 8
constexpr int F   = 2 * FL + QS;  // 40
constexpr int HF  = H * F;        // 1280
constexpr int JC  = HF / 4;       // 320
constexpr int WP  = W + 2;        // 194 padded row
constexpr int HWP = H * WP;

// ---- workspace layout (floats), lifetime-overlapped ----------------------
// timeline: prep_x(XP) -> zero(KV-pads,zrow) -> qkv(read XP, write Q,K,V)
//        -> build_kv(read K,V, write KVI over XP) -> attn(read Q,KVI, write O over K)
//        -> out_conv(read O)
constexpr size_t XP_OFF  = 0;                         // 794,624  [b][64][32][194]
constexpr size_t KVI_OFF = 0;                         // 1,310,720 (over XP, XP dead)
constexpr size_t Q_OFF   = 1310720;                   // 393,216
constexpr size_t K_OFF   = Q_OFF + 393216;            // 1,703,936 ; 425,984
constexpr size_t V_OFF   = K_OFF + 425984;            // 2,129,920 ; 425,984
constexpr size_t O_OFF   = K_OFF;                     // 397,312 (over K, K dead)
constexpr size_t ZR_OFF  = V_OFF + 425984;            // 2,555,904 ; 256 zeros
// total = 2,556,160 floats = 10.22 MB

// strides of the faithful as_strided-bug gather (uses T=192, not TP=208!)
constexpr int S0 = NH * C * H * T; // 196608
constexpr int S1 = C * H * T;      // 24576
constexpr int S2 = H * T;          // 6144
constexpr int S3 = T;              // 192
}

// ---- build x padded along W: xp[b][ci][y][0..193], cols 0/193 = 0 --------
__global__ __launch_bounds__(256) void prep_x_k(const float* __restrict__ x,
                                                float* __restrict__ ws) {
  int row = blockIdx.x;                  // 0..4095 = (b*64+ci)*32+y
  int c = threadIdx.x;                   // 0..255
  if (c >= WP) return;
  float v = (c == 0 || c == WP - 1) ? 0.f : x[(size_t)row * W + (c - 1)];
  ws[XP_OFF + (size_t)row * WP + c] = v;
}

// ---- zero K/V pad columns + the zero-row page ----------------------------
__global__ __launch_bounds__(256) void zero_pads_k(float* __restrict__ ws) {
  int t = blockIdx.x * 256 + threadIdx.x;
  if (t < 32768) {                       // K/V pads: 2048 rows x 16 pad cols
    int row = t >> 4;
    int p = t & 15;
    int col = (p < 8) ? p : (192 + p);
    size_t addr = (size_t)row * TP + col;
    ws[K_OFF + addr] = 0.f;
    ws[V_OFF + addr] = 0.f;
  } else if (t < 32768 + 256) {
    ws[ZR_OFF + (t - 32768)] = 0.f;
  }
}

// ---- fused q/k/v conv3x3: branchless inner loop --------------------------
// block (b,co,y), 192 threads = one x each
__global__ __launch_bounds__(192) void qkv_conv_k(
    const float* __restrict__ qw, const float* __restrict__ qb,
    const float* __restrict__ kw, const float* __restrict__ kb,
    const float* __restrict__ vw, const float* __restrict__ vb,
    float* __restrict__ ws) {
  int bid = blockIdx.x;
  int y  = bid & 31;
  int co = (bid >> 5) & 31;
  int b  = bid >> 10;
  int xp = threadIdx.x;

  const float* zr  = ws + ZR_OFF;
  const float* xpb = ws + XP_OFF + (size_t)b * CIN * HWP;

  const float* p0; const float* p1; const float* p2;
  int st0, st2;
  p1 = xpb + y * WP;
  if (y > 0)     { p0 = xpb + (y - 1) * WP; st0 = HWP; } else { p0 = zr; st0 = 0; }
  if (y < H - 1) { p2 = xpb + (y + 1) * WP; st2 = HWP; } else { p2 = zr; st2 = 0; }

  const float* wq = qw + co * (CIN * 9);
  const float* wk = kw + co * (CIN * 9);
  const float* wv = vw + co * (CIN * 9);
  float aq = qb[co], ak = kb[co], av = vb[co];

#pragma unroll 2
  for (int ci = 0; ci < CIN; ++ci) {
    float a0 = p0[xp], a1 = p0[xp + 1], a2 = p0[xp + 2];
    float b0 = p1[xp], b1 = p1[xp + 1], b2 = p1[xp + 2];
    float c0 = p2[xp], c1 = p2[xp + 1], c2 = p2[xp + 2];

    aq = fmaf(a0, wq[0], aq); ak = fmaf(a0, wk[0], ak); av = fmaf(a0, wv[0], av);
    aq = fmaf(a1, wq[1], aq); ak = fmaf(a1, wk[1], ak); av = fmaf(a1, wv[1], av);
    aq = fmaf(a2, wq[2], aq); ak = fmaf(a2, wk[2], ak); av = fmaf(a2, wv[2], av);
    aq = fmaf(b0, wq[3], aq); ak = fmaf(b0, wk[3], ak); av = fmaf(b0, wv[3], av);
    aq = fmaf(b1, wq[4], aq); ak = fmaf(b1, wk[4], ak); av = fmaf(b1, wv[4], av);
    aq = fmaf(b2, wq[5], aq); ak = fmaf(b2, wk[5], ak); av = fmaf(b2, wv[5], av);
    aq = fmaf(c0, wq[6], aq); ak = fmaf(c0, wk[6], ak); av = fmaf(c0, wv[6], av);
    aq = fmaf(c1, wq[7], aq); ak = fmaf(c1, wk[7], ak); av = fmaf(c1, wv[7], av);
    aq = fmaf(c2, wq[8], aq); ak = fmaf(c2, wk[8], ak); av = fmaf(c2, wv[8], av);

    p0 += st0; p1 += HWP; p2 += st2;
    wq += 9; wk += 9; wv += 9;
  }

  ws[Q_OFF + ((size_t)(b * DM + co) * H + y) * T + xp] = aq;
  int h = co >> 2, c4 = co & 3;
  size_t pa = ((size_t)((b * NH + h) * C + c4) * H + y) * TP + FL + xp;
  ws[K_OFF + pa] = ak;
  ws[V_OFF + pa] = av;
}

// ---- build interleaved KV windows: kvi[g][j][k0..k3,v0..v3] --------------
__global__ __launch_bounds__(256) void build_kv_k(float* __restrict__ ws) {
  const float* kp = ws + K_OFF;
  const float* vp = ws + V_OFF;
  float* kvi = ws + KVI_OFF;
  int t = blockIdx.x * 256 + threadIdx.x;       // < 1,310,720
  int c  = t & 7;
  int gj = t >> 3;
  int g  = gj / HF;
  int j  = gj - g * HF;
  int b = g >> 6, h = (g >> 3) & 7, m = g & 7;
  int hh = j / F, f = j - hh * F;
  int ci = c & 3;
  const float* src = (c < 4) ? kp : vp;
  int addr = b * S0 + h * S1 + ci * S2 + hh * S3 + m * QS + f;
  kvi[t] = src[addr];
}

// ---- attention: block = 4 j-chunk waves x 64 rows; writes padded O -------
__global__ __launch_bounds__(256) void attn_k(float* __restrict__ ws) {
  const float* qbuf = ws + Q_OFF;
  const float* kvi  = ws + KVI_OFF;
  float*       ob   = ws + O_OFF;

  int g  = blockIdx.x;                          // 0..127
  int rb = blockIdx.y;                          // 0..11
  int b = g >> 6, h = (g >> 3) & 7, m = g & 7;
  int tid = threadIdx.x;
  int row = tid & 63;
  int jc  = __builtin_amdgcn_readfirstlane(tid >> 6);

  int r  = rb * 64 + row;                       // 0..767
  int hh = r / QS, qi = r - hh * QS;
  size_t qidx = (((size_t)(b * DM + h * C) * H + hh) * T) + m * QS + qi;
  float q0 = qbuf[qidx]             * 0.5f;
  float q1 = qbuf[qidx + H * T]     * 0.5f;
  float q2 = qbuf[qidx + 2 * H * T] * 0.5f;
  float q3 = qbuf[qidx + 3 * H * T] * 0.5f;

  const float* kvp = kvi + ((size_t)g * HF + (size_t)jc * JC) * 8;

  float s = 0.f, o0 = 0.f, o1 = 0.f, o2 = 0.f, o3 = 0.f;
#pragma unroll 4
  for (int j = 0; j < JC; ++j) {
    float4 k4 = *reinterpret_cast<const float4*>(kvp + j * 8);
    float4 v4 = *reinterpret_cast<const float4*>(kvp + j * 8 + 4);
    float l = fmaf(q0, k4.x, fmaf(q1, k4.y, fmaf(q2, k4.z, q3 * k4.w)));
    float e = __expf(l);
    s += e;
    o0 = fmaf(e, v4.x, o0);
    o1 = fmaf(e, v4.y, o1);
    o2 = fmaf(e, v4.z, o2);
    o3 = fmaf(e, v4.w, o3);
  }

  __shared__ float red[4][64][5];
  red[jc][row][0] = s;
  red[jc][row][1] = o0;
  red[jc][row][2] = o1;
  red[jc][row][3] = o2;
  red[jc][row][4] = o3;
  __syncthreads();

  if (tid < 64) {
    float S = 0.f, O0 = 0.f, O1 = 0.f, O2 = 0.f, O3 = 0.f;
#pragma unroll
    for (int cx = 0; cx < 4; ++cx) {
      S  += red[cx][tid][0];
      O0 += red[cx][tid][1];
      O1 += red[cx][tid][2];
      O2 += red[cx][tid][3];
      O3 += red[cx][tid][4];
    }
    float inv = 1.0f / S;
    // padded O: row stride WP, interior offset +1
    size_t obase = (((size_t)(b * DM + h * C) * H + hh) * WP) + 1 + m * QS + qi;
    ob[obase]            = O0 * inv;
    ob[obase + HWP]      = O1 * inv;
    ob[obase + 2 * HWP]  = O2 * inv;
    ob[obase + 3 * HWP]  = O3 * inv;
    // zero the pad columns of this O row (cols 0 and 193)
    if (m == 0 && qi == 0) {
      ob[obase - 1] = 0.f; ob[obase - 1 + HWP] = 0.f;
      ob[obase - 1 + 2 * HWP] = 0.f; ob[obase - 1 + 3 * HWP] = 0.f;
    }
    if (m == M - 1 && qi == QS - 1) {
      ob[obase + 1] = 0.f; ob[obase + 1 + HWP] = 0.f;
      ob[obase + 1 + 2 * HWP] = 0.f; ob[obase + 1 + 3 * HWP] = 0.f;
    }
  }
}

// ---- output conv3x3 (32 -> 64): branchless, 4 co per thread --------------
// block (b, co-quad, y), 192 threads
__global__ __launch_bounds__(192) void out_conv_k(const float* __restrict__ ws,
                                                  const float* __restrict__ ow,
                                                  float* __restrict__ out) {
  int bid = blockIdx.x;
  int y  = bid & 31;
  int cq = (bid >> 5) & 15;
  int b  = bid >> 9;
  int xp = threadIdx.x;

  const float* zr  = ws + ZR_OFF;
  const float* obb = ws + O_OFF + (size_t)b * DM * HWP;

  const float* p0; const float* p1; const float* p2;
  int st0, st2;
  p1 = obb + y * WP;
  if (y > 0)     { p0 = obb + (y - 1) * WP; st0 = HWP; } else { p0 = zr; st0 = 0; }
  if (y < H - 1) { p2 = obb + (y + 1) * WP; st2 = HWP; } else { p2 = zr; st2 = 0; }

  int co0 = cq * 4;
  const float* w0 = ow + (size_t)(co0 + 0) * (DM * 9);
  const float* w1 = ow + (size_t)(co0 + 1) * (DM * 9);
  const float* w2 = ow + (size_t)(co0 + 2) * (DM * 9);
  const float* w3 = ow + (size_t)(co0 + 3) * (DM * 9);
  float A0 = 0.f, A1 = 0.f, A2 = 0.f, A3 = 0.f;

#pragma unroll 2
  for (int ci = 0; ci < DM; ++ci) {
    float a0 = p0[xp], a1 = p0[xp + 1], a2 = p0[xp + 2];
    float b0 = p1[xp], b1 = p1[xp + 1], b2 = p1[xp + 2];
    float c0 = p2[xp], c1 = p2[xp + 1], c2 = p2[xp + 2];

    A0 = fmaf(a0, w0[0], A0); A1 = fmaf(a0, w1[0], A1); A2 = fmaf(a0, w2[0], A2); A3 = fmaf(a0, w3[0], A3);
    A0 = fmaf(a1, w0[1], A0); A1 = fmaf(a1, w1[1], A1); A2 = fmaf(a1, w2[1], A2); A3 = fmaf(a1, w3[1], A3);
    A0 = fmaf(a2, w0[2], A0); A1 = fmaf(a2, w1[2], A1); A2 = fmaf(a2, w2[2], A2); A3 = fmaf(a2, w3[2], A3);
    A0 = fmaf(b0, w0[3], A0); A1 = fmaf(b0, w1[3], A1); A2 = fmaf(b0, w2[3], A2); A3 = fmaf(b0, w3[3], A3);
    A0 = fmaf(b1, w0[4], A0); A1 = fmaf(b1, w1[4], A1); A2 = fmaf(b1, w2[4], A2); A3 = fmaf(b1, w3[4], A3);
    A0 = fmaf(b2, w0[5], A0); A1 = fmaf(b2, w1[5], A1); A2 = fmaf(b2, w2[5], A2); A3 = fmaf(b2, w3[5], A3);
    A0 = fmaf(c0, w0[6], A0); A1 = fmaf(c0, w1[6], A1); A2 = fmaf(c0, w2[6], A2); A3 = fmaf(c0, w3[6], A3);
    A0 = fmaf(c1, w0[7], A0); A1 = fmaf(c1, w1[7], A1); A2 = fmaf(c1, w2[7], A2); A3 = fmaf(c1, w3[7], A3);
    A0 = fmaf(c2, w0[8], A0); A1 = fmaf(c2, w1[8], A1); A2 = fmaf(c2, w2[8], A2); A3 = fmaf(c2, w3[8], A3);

    p0 += st0; p1 += HWP; p2 += st2;
    w0 += 9; w1 += 9; w2 += 9; w3 += 9;
  }

  size_t ob0 = ((size_t)(b * 64 + co0) * H + y) * W + xp;
  out[ob0]           = A0;
  out[ob0 + H * W]   = A1;
  out[ob0 + 2*H*W]   = A2;
  out[ob0 + 3*H*W]   = A3;
}

extern "C" void kernel_launch(void* const* d_in, const int* in_sizes, int n_in,
                              void* d_out, int out_size, void* d_ws, size_t ws_size,
                              hipStream_t stream) {
  const float* x  = (const float*)d_in[0];
  const float* qw = (const float*)d_in[1];
  const float* qb = (const float*)d_in[2];
  const float* kw = (const float*)d_in[3];
  const float* kb = (const float*)d_in[4];
  const float* vw = (const float*)d_in[5];
  const float* vb = (const float*)d_in[6];
  const float* ow = (const float*)d_in[7];
  float* out = (float*)d_out;
  float* ws  = (float*)d_ws;

  hipLaunchKernelGGL(prep_x_k,   dim3(B * CIN * H), dim3(256), 0, stream, x, ws);
  hipLaunchKernelGGL(zero_pads_k, dim3(130), dim3(256), 0, stream, ws);
  hipLaunchKernelGGL(qkv_conv_k, dim3(B * 32 * 32), dim3(192), 0, stream,
                     qw, qb, kw, kb, vw, vb, ws);
  hipLaunchKernelGGL(build_kv_k, dim3(5120), dim3(256), 0, stream, ws);
  hipLaunchKernelGGL(attn_k,     dim3(128, 12), dim3(256), 0, stream, ws);
  hipLaunchKernelGGL(out_conv_k, dim3(B * 16 * 32), dim3(192), 0, stream, ws, ow, out);
}

// Round 4
// 100.305 us; speedup vs baseline: 2.6699x; 1.1723x over previous
//
#include <hip/hip_runtime.h>

namespace {
constexpr int B   = 2;
constexpr int CIN = 64;
constexpr int H   = 32;
constexpr int W   = 192;
constexpr int DM  = 32;
constexpr int NH  = 8;
constexpr int C   = 4;
constexpr int QS  = 24;
constexpr int FL  = 8;
constexpr int T   = 192;
constexpr int TP  = T + 2 * FL;   // 208
constexpr int M   = T / QS;       // 8
constexpr int F   = 2 * FL + QS;  // 40
constexpr int HF  = H * F;        // 1280
constexpr int JC  = HF / 4;       // 320
constexpr int WP  = 196;          // padded row (16B-aligned pitch: 784B)
constexpr int HWP = H * WP;       // 6272

// ---- workspace layout (floats), lifetime-overlapped ----------------------
// prep(XP, KVpads, zr) -> qkv(XP -> Q,K,V) -> build_kv(K,V -> KVI over XP)
// -> attn(Q,KVI -> O over K) -> out_conv(O -> out)
constexpr size_t XP_OFF  = 0;                          // 802,816
constexpr size_t KVI_OFF = 0;                          // 1,310,720 (XP dead)
constexpr size_t Q_OFF   = 1310720;                    // 393,216
constexpr size_t K_OFF   = Q_OFF + 393216;             // 1,703,936 ; 425,984
constexpr size_t V_OFF   = K_OFF + 425984;             // 2,129,920 ; 425,984
constexpr size_t O_OFF   = K_OFF;                      // 401,408 (K dead)
constexpr size_t ZR_OFF  = V_OFF + 425984;             // 2,555,904 ; 256 zeros
// total = 2,556,160 floats = 10.22 MB

// strides of the faithful as_strided-bug gather (uses T=192, not TP=208!)
constexpr int S0 = NH * C * H * T; // 196608
constexpr int S1 = C * H * T;      // 24576
constexpr int S2 = H * T;          // 6144
constexpr int S3 = T;              // 192
}

// ---- fused prep: pad x rows to 196 + zero K/V pad cols + zero-row page ---
__global__ __launch_bounds__(256) void prep_k(const float* __restrict__ x,
                                              float* __restrict__ ws) {
  int bid = blockIdx.x;
  int tid = threadIdx.x;
  if (bid < 4096) {                       // x rows: (b*64+ci)*32+y
    if (tid < WP) {
      float v = (tid >= 1 && tid <= W) ? x[(size_t)bid * W + (tid - 1)] : 0.f;
      ws[XP_OFF + (size_t)bid * WP + tid] = v;
    }
  } else if (bid < 4224) {                // K/V pad cols: 2048 rows x 16
    int t = (bid - 4096) * 256 + tid;
    int row = t >> 4;
    int p = t & 15;
    int col = (p < 8) ? p : (192 + p);
    size_t addr = (size_t)row * TP + col;
    ws[K_OFF + addr] = 0.f;
    ws[V_OFF + addr] = 0.f;
  } else {                                // zero-row page
    ws[ZR_OFF + tid] = 0.f;
  }
}

// ---- fused q/k/v conv3x3: 4 x-positions per thread -----------------------
// block (b, co, y-quad), 192 threads: ylocal = tid/48, xq = tid%48
__global__ __launch_bounds__(192) void qkv_conv_k(
    const float* __restrict__ qw, const float* __restrict__ qb,
    const float* __restrict__ kw, const float* __restrict__ kb,
    const float* __restrict__ vw, const float* __restrict__ vb,
    float* __restrict__ ws) {
  int bid = blockIdx.x;
  int yq = bid & 7;
  int co = (bid >> 3) & 31;
  int b  = bid >> 8;
  int tid = threadIdx.x;
  int yl = tid / 48;
  int xq = tid - yl * 48;
  int y  = yq * 4 + yl;
  int xp = xq * 4;

  const float* zr  = ws + ZR_OFF;
  const float* xpb = ws + XP_OFF + (size_t)b * CIN * HWP;

  const float* p0 = (y > 0)     ? xpb + (y - 1) * WP + xp : zr + xp;
  const float* p1 = xpb + y * WP + xp;
  const float* p2 = (y < H - 1) ? xpb + (y + 1) * WP + xp : zr + xp;
  int st0 = (y > 0)     ? HWP : 0;
  int st2 = (y < H - 1) ? HWP : 0;

  const float* wq = qw + co * (CIN * 9);
  const float* wk = kw + co * (CIN * 9);
  const float* wv = vw + co * (CIN * 9);

  float q0b = qb[co], k0b = kb[co], v0b = vb[co];
  float Aq[4] = {q0b, q0b, q0b, q0b};
  float Ak[4] = {k0b, k0b, k0b, k0b};
  float Av[4] = {v0b, v0b, v0b, v0b};

#pragma unroll 2
  for (int ci = 0; ci < CIN; ++ci) {
    float4 a4 = *reinterpret_cast<const float4*>(p0);
    float2 a2 = *reinterpret_cast<const float2*>(p0 + 4);
    float4 b4 = *reinterpret_cast<const float4*>(p1);
    float2 b2 = *reinterpret_cast<const float2*>(p1 + 4);
    float4 c4 = *reinterpret_cast<const float4*>(p2);
    float2 c2 = *reinterpret_cast<const float2*>(p2 + 4);
    float av_[6] = {a4.x, a4.y, a4.z, a4.w, a2.x, a2.y};
    float bv_[6] = {b4.x, b4.y, b4.z, b4.w, b2.x, b2.y};
    float cv_[6] = {c4.x, c4.y, c4.z, c4.w, c2.x, c2.y};
#pragma unroll
    for (int dx = 0; dx < 3; ++dx) {
      float wq0 = wq[dx], wq1 = wq[3 + dx], wq2 = wq[6 + dx];
      float wk0 = wk[dx], wk1 = wk[3 + dx], wk2 = wk[6 + dx];
      float wv0 = wv[dx], wv1 = wv[3 + dx], wv2 = wv[6 + dx];
#pragma unroll
      for (int o = 0; o < 4; ++o) {
        float xa = av_[o + dx], xb = bv_[o + dx], xc = cv_[o + dx];
        Aq[o] = fmaf(xa, wq0, Aq[o]); Aq[o] = fmaf(xb, wq1, Aq[o]); Aq[o] = fmaf(xc, wq2, Aq[o]);
        Ak[o] = fmaf(xa, wk0, Ak[o]); Ak[o] = fmaf(xb, wk1, Ak[o]); Ak[o] = fmaf(xc, wk2, Ak[o]);
        Av[o] = fmaf(xa, wv0, Av[o]); Av[o] = fmaf(xb, wv1, Av[o]); Av[o] = fmaf(xc, wv2, Av[o]);
      }
    }
    p0 += st0; p1 += HWP; p2 += st2;
    wq += 9; wk += 9; wv += 9;
  }

  *reinterpret_cast<float4*>(ws + Q_OFF + ((size_t)(b * DM + co) * H + y) * T + xp) =
      make_float4(Aq[0], Aq[1], Aq[2], Aq[3]);
  int h = co >> 2, c4i = co & 3;
  size_t pa = ((size_t)((b * NH + h) * C + c4i) * H + y) * TP + FL + xp;
  *reinterpret_cast<float4*>(ws + K_OFF + pa) = make_float4(Ak[0], Ak[1], Ak[2], Ak[3]);
  *reinterpret_cast<float4*>(ws + V_OFF + pa) = make_float4(Av[0], Av[1], Av[2], Av[3]);
}

// ---- build interleaved KV windows: kvi[g][j][k0..k3,v0..v3] --------------
__global__ __launch_bounds__(256) void build_kv_k(float* __restrict__ ws) {
  const float* kp = ws + K_OFF;
  const float* vp = ws + V_OFF;
  float* kvi = ws + KVI_OFF;
  int t = blockIdx.x * 256 + threadIdx.x;       // < 1,310,720
  int c  = t & 7;
  int gj = t >> 3;
  int g  = gj / HF;
  int j  = gj - g * HF;
  int b = g >> 6, h = (g >> 3) & 7, m = g & 7;
  int hh = j / F, f = j - hh * F;
  int ci = c & 3;
  const float* src = (c < 4) ? kp : vp;
  int addr = b * S0 + h * S1 + ci * S2 + hh * S3 + m * QS + f;
  kvi[t] = src[addr];
}

// ---- attention: block = 4 j-chunk waves x 64 rows; writes padded O -------
__global__ __launch_bounds__(256) void attn_k(float* __restrict__ ws) {
  const float* qbuf = ws + Q_OFF;
  const float* kvi  = ws + KVI_OFF;
  float*       ob   = ws + O_OFF;

  int g  = blockIdx.x;                          // 0..127
  int rb = blockIdx.y;                          // 0..11
  int b = g >> 6, h = (g >> 3) & 7, m = g & 7;
  int tid = threadIdx.x;
  int row = tid & 63;
  int jc  = __builtin_amdgcn_readfirstlane(tid >> 6);

  int r  = rb * 64 + row;                       // 0..767
  int hh = r / QS, qi = r - hh * QS;
  size_t qidx = (((size_t)(b * DM + h * C) * H + hh) * T) + m * QS + qi;
  float q0 = qbuf[qidx]             * 0.5f;
  float q1 = qbuf[qidx + H * T]     * 0.5f;
  float q2 = qbuf[qidx + 2 * H * T] * 0.5f;
  float q3 = qbuf[qidx + 3 * H * T] * 0.5f;

  const float* kvp = kvi + ((size_t)g * HF + (size_t)jc * JC) * 8;

  float s = 0.f, o0 = 0.f, o1 = 0.f, o2 = 0.f, o3 = 0.f;
#pragma unroll 4
  for (int j = 0; j < JC; ++j) {
    float4 k4 = *reinterpret_cast<const float4*>(kvp + j * 8);
    float4 v4 = *reinterpret_cast<const float4*>(kvp + j * 8 + 4);
    float l = fmaf(q0, k4.x, fmaf(q1, k4.y, fmaf(q2, k4.z, q3 * k4.w)));
    float e = __expf(l);
    s += e;
    o0 = fmaf(e, v4.x, o0);
    o1 = fmaf(e, v4.y, o1);
    o2 = fmaf(e, v4.z, o2);
    o3 = fmaf(e, v4.w, o3);
  }

  __shared__ float red[4][64][5];
  red[jc][row][0] = s;
  red[jc][row][1] = o0;
  red[jc][row][2] = o1;
  red[jc][row][3] = o2;
  red[jc][row][4] = o3;
  __syncthreads();

  if (tid < 64) {
    float S = 0.f, O0 = 0.f, O1 = 0.f, O2 = 0.f, O3 = 0.f;
#pragma unroll
    for (int cx = 0; cx < 4; ++cx) {
      S  += red[cx][tid][0];
      O0 += red[cx][tid][1];
      O1 += red[cx][tid][2];
      O2 += red[cx][tid][3];
      O3 += red[cx][tid][4];
    }
    float inv = 1.0f / S;
    // padded O: row stride WP=196, interior offset +1
    size_t obase = (((size_t)(b * DM + h * C) * H + hh) * WP) + 1 + m * QS + qi;
    ob[obase]            = O0 * inv;
    ob[obase + HWP]      = O1 * inv;
    ob[obase + 2 * HWP]  = O2 * inv;
    ob[obase + 3 * HWP]  = O3 * inv;
    if (m == 0 && qi == 0) {                    // zero pad col 0
      ob[obase - 1] = 0.f; ob[obase - 1 + HWP] = 0.f;
      ob[obase - 1 + 2 * HWP] = 0.f; ob[obase - 1 + 3 * HWP] = 0.f;
    }
    if (m == M - 1 && qi == QS - 1) {           // zero pad col 193
      ob[obase + 1] = 0.f; ob[obase + 1 + HWP] = 0.f;
      ob[obase + 1 + 2 * HWP] = 0.f; ob[obase + 1 + 3 * HWP] = 0.f;
    }
  }
}

// ---- output conv3x3 (32 -> 64): 2 co x 4 x-positions per thread ----------
// block (b, co-pair, y-quad), 192 threads
__global__ __launch_bounds__(192) void out_conv_k(const float* __restrict__ ws,
                                                  const float* __restrict__ ow,
                                                  float* __restrict__ out) {
  int bid = blockIdx.x;
  int yq = bid & 7;
  int cp = (bid >> 3) & 31;
  int b  = bid >> 8;
  int tid = threadIdx.x;
  int yl = tid / 48;
  int xq = tid - yl * 48;
  int y  = yq * 4 + yl;
  int xp = xq * 4;

  const float* zr  = ws + ZR_OFF;
  const float* obb = ws + O_OFF + (size_t)b * DM * HWP;

  const float* p0 = (y > 0)     ? obb + (y - 1) * WP + xp : zr + xp;
  const float* p1 = obb + y * WP + xp;
  const float* p2 = (y < H - 1) ? obb + (y + 1) * WP + xp : zr + xp;
  int st0 = (y > 0)     ? HWP : 0;
  int st2 = (y < H - 1) ? HWP : 0;

  int co0 = cp * 2;
  const float* w0 = ow + (size_t)co0 * (DM * 9);
  const float* w1 = w0 + DM * 9;
  float A0[4] = {0.f, 0.f, 0.f, 0.f};
  float A1[4] = {0.f, 0.f, 0.f, 0.f};

#pragma unroll 2
  for (int ci = 0; ci < DM; ++ci) {
    float4 a4 = *reinterpret_cast<const float4*>(p0);
    float2 a2 = *reinterpret_cast<const float2*>(p0 + 4);
    float4 b4 = *reinterpret_cast<const float4*>(p1);
    float2 b2 = *reinterpret_cast<const float2*>(p1 + 4);
    float4 c4 = *reinterpret_cast<const float4*>(p2);
    float2 c2 = *reinterpret_cast<const float2*>(p2 + 4);
    float av_[6] = {a4.x, a4.y, a4.z, a4.w, a2.x, a2.y};
    float bv_[6] = {b4.x, b4.y, b4.z, b4.w, b2.x, b2.y};
    float cv_[6] = {c4.x, c4.y, c4.z, c4.w, c2.x, c2.y};
#pragma unroll
    for (int dx = 0; dx < 3; ++dx) {
      float u0 = w0[dx], u1 = w0[3 + dx], u2 = w0[6 + dx];
      float t0 = w1[dx], t1 = w1[3 + dx], t2 = w1[6 + dx];
#pragma unroll
      for (int o = 0; o < 4; ++o) {
        float xa = av_[o + dx], xb = bv_[o + dx], xc = cv_[o + dx];
        A0[o] = fmaf(xa, u0, A0[o]); A0[o] = fmaf(xb, u1, A0[o]); A0[o] = fmaf(xc, u2, A0[o]);
        A1[o] = fmaf(xa, t0, A1[o]); A1[o] = fmaf(xb, t1, A1[o]); A1[o] = fmaf(xc, t2, A1[o]);
      }
    }
    p0 += st0; p1 += HWP; p2 += st2;
    w0 += 9; w1 += 9;
  }

  size_t ob0 = ((size_t)(b * 64 + co0) * H + y) * W + xp;
  *reinterpret_cast<float4*>(out + ob0)         = make_float4(A0[0], A0[1], A0[2], A0[3]);
  *reinterpret_cast<float4*>(out + ob0 + H * W) = make_float4(A1[0], A1[1], A1[2], A1[3]);
}

extern "C" void kernel_launch(void* const* d_in, const int* in_sizes, int n_in,
                              void* d_out, int out_size, void* d_ws, size_t ws_size,
                              hipStream_t stream) {
  const float* x  = (const float*)d_in[0];
  const float* qw = (const float*)d_in[1];
  const float* qb = (const float*)d_in[2];
  const float* kw = (const float*)d_in[3];
  const float* kb = (const float*)d_in[4];
  const float* vw = (const float*)d_in[5];
  const float* vb = (const float*)d_in[6];
  const float* ow = (const float*)d_in[7];
  float* out = (float*)d_out;
  float* ws  = (float*)d_ws;

  hipLaunchKernelGGL(prep_k,     dim3(4225), dim3(256), 0, stream, x, ws);
  hipLaunchKernelGGL(qkv_conv_k, dim3(512),  dim3(192), 0, stream,
                     qw, qb, kw, kb, vw, vb, ws);
  hipLaunchKernelGGL(build_kv_k, dim3(5120), dim3(256), 0, stream, ws);
  hipLaunchKernelGGL(attn_k,     dim3(128, 12), dim3(256), 0, stream, ws);
  hipLaunchKernelGGL(out_conv_k, dim3(512),  dim3(192), 0, stream, ws, ow, out);
}